// Round 6
// baseline (356.700 us; speedup 1.0000x reference)
//
#include <hip/hip_runtime.h>

#define TT   256
#define HID  30
#define LOG2E 1.4426950408889634f
#define HS   56        // h-row stride in bf16: 112B -> b128 reads 2-way (free)
#define XROW (TT*3)

typedef __bf16 bf16x8_t __attribute__((ext_vector_type(8)));
typedef float  f32x4_t  __attribute__((ext_vector_type(4)));

__device__ __forceinline__ float fexp2(float x){
#if __has_builtin(__builtin_amdgcn_exp2f)
    return __builtin_amdgcn_exp2f(x);
#else
    return exp2f(x);
#endif
}
__device__ __forceinline__ float frcp(float x){
#if __has_builtin(__builtin_amdgcn_rcpf)
    return __builtin_amdgcn_rcpf(x);
#else
    return 1.f/x;
#endif
}
__device__ __forceinline__ float fsigmoid(float x){ return frcp(1.f + fexp2(-LOG2E*x)); }
__device__ __forceinline__ float ftanh_f(float x){ return 2.f*frcp(1.f + fexp2(-2.f*LOG2E*x)) - 1.f; }
__device__ __forceinline__ f32x4_t exp4(f32x4_t v){
    f32x4_t e; e[0]=fexp2(v[0]); e[1]=fexp2(v[1]); e[2]=fexp2(v[2]); e[3]=fexp2(v[3]); return e;
}
__device__ __forceinline__ f32x4_t rcp4(f32x4_t v){
    f32x4_t r; r[0]=frcp(v[0]); r[1]=frcp(v[1]); r[2]=frcp(v[2]); r[3]=frcp(v[3]); return r;
}

#define MFMA(A,B,C) __builtin_amdgcn_mfma_f32_16x16x32_bf16(A,B,C,0,0,0)

// Dual-stream wave-specialized skewed 2-layer LSTM.
// Block = 512 threads = 8 waves, owns 32 batch rows as TWO independent
// 16-row streams (X=rows 0-15, Y=rows 16-31) sharing weight fragments.
// Waves 0-3: layer0(t=s+1) both streams; waves 4-7: layer1(t=s) both.
// One barrier per step serves both streams; the two streams' chains
// interleave inside each wave to hide MFMA/trans/DS latency.
__global__ __launch_bounds__(512, 2)
void lstm_fused(const float* __restrict__ x,
    const float* __restrict__ Wih0, const float* __restrict__ Whh0,
    const float* __restrict__ bih0, const float* __restrict__ bhh0,
    const float* __restrict__ Wih1, const float* __restrict__ Whh1,
    const float* __restrict__ bih1, const float* __restrict__ bhh1,
    const float* __restrict__ Wfc1, const float* __restrict__ bfc1,
    const float* __restrict__ Wfc2, const float* __restrict__ bfc2,
    const float* __restrict__ Wfc3, const float* __restrict__ bfc3,
    float* __restrict__ out)
{
    __shared__ __align__(16) __bf16 h0f[2][2][16][HS]; // [stream][buf][m][k]; k30,31: x0,x1
    __shared__ __align__(16) __bf16 h1f[2][2][16][HS];
    __shared__ float h1_last[32*32];
    __shared__ float zbuf[32*64];
    __shared__ float z2buf[32*32];

    const int tid  = threadIdx.x;
    const int lane = tid & 63;
    const int wvf  = tid >> 6;
    const bool grpA = (wvf < 4);
    const int wv   = wvf & 3;
    const int n    = lane & 15;
    const int q    = lane >> 4;
    const int nl   = n & 7;
    const int u    = wv*8 + nl;        // hidden unit
    const int hi   = n >> 3;           // 0:{i,g} 1:{f,o}
    const bool colok = (u < HID);
    const int bbase = blockIdx.x * 32;

    const int uq  = colok ? u : 0;
    const int wr0 = (hi ? 1 : 0)*HID + uq;    // i/f row
    const int wr1 = (hi ? 3 : 2)*HID + uq;    // g/o row

    // ---- group-specialized resident B-fragments (shared by both streams) ----
    bf16x8_t fbA{}, fbB{}, fbC{}, fbD{};
    float b0=0.f, b1=0.f, wx20=0.f, wx21=0.f;
    if (grpA) {
        #pragma unroll
        for (int j = 0; j < 8; ++j) {
            int k = q*8 + j;
            float v0=0.f, v1=0.f;
            if (colok) {
                if (k < HID) { v0 = Whh0[wr0*HID+k];      v1 = Whh0[wr1*HID+k]; }
                else         { v0 = Wih0[wr0*3+(k-HID)];  v1 = Wih0[wr1*3+(k-HID)]; }
            }
            fbA[j]=(__bf16)v0; fbB[j]=(__bf16)v1;
        }
        if (colok) {
            b0 = bih0[wr0] + bhh0[wr0];
            b1 = bih0[wr1] + bhh0[wr1];
            wx20 = Wih0[wr0*3+2];  wx21 = Wih0[wr1*3+2];
        }
    } else {
        #pragma unroll
        for (int j = 0; j < 8; ++j) {
            int k = q*8 + j;
            float v0=0.f, v1=0.f, v2=0.f, v3=0.f;
            if (colok && k < HID) {
                v0 = Wih1[wr0*HID+k];  v1 = Wih1[wr1*HID+k];
                v2 = Whh1[wr0*HID+k];  v3 = Whh1[wr1*HID+k];
            }
            fbA[j]=(__bf16)v0; fbB[j]=(__bf16)v1;
            fbC[j]=(__bf16)v2; fbD[j]=(__bf16)v3;
        }
        if (colok) {
            b0 = bih1[wr0] + bhh1[wr0];
            b1 = bih1[wr1] + bhh1[wr1];
        }
    }
    const f32x4_t bv0 = {b0,b0,b0,b0};
    const f32x4_t bv1 = {b1,b1,b1,b1};
    const float mco1 = (hi==0) ? (-2.f*LOG2E) : (-LOG2E);  // g=tanh | o=sigm
    const float aco1 = (hi==0) ? 2.f : 1.f;
    const float bco1 = (hi==0) ? -1.f : 0.f;

    f32x4_t cst[2] = {{0.f,0.f,0.f,0.f},{0.f,0.f,0.f,0.f}};

    for (int i = tid; i < 2*2*16*HS; i += 512) {
        (&h0f[0][0][0][0])[i] = (__bf16)0.f;
        (&h1f[0][0][0][0])[i] = (__bf16)0.f;
    }
    __syncthreads();
    if (tid < 64) {    // x0,x1(t=0) into prologue read-buffer (buf 1), both streams
        int m = tid >> 1, cc = tid & 1;          // m 0..31
        h0f[m>>4][1][m&15][30+cc] = (__bf16)x[(size_t)(bbase+m)*XROW + cc];
    }
    __syncthreads();

    // x addressing: SGPR base + fixed VGPR offsets
    const float* xB = x + (size_t)bbase*XROW;
    const int xo2  = (q*4)*XROW + 2;             // + r*XROW, stream Y adds 16*XROW
    const int xo01 = (tid>>1)*XROW + (tid&1);    // covers 32 rows over lanes 0..63
    f32x4_t x2[2] = {{0.f,0.f,0.f,0.f},{0.f,0.f,0.f,0.f}};
    if (grpA) {
        #pragma unroll
        for (int r=0;r<4;++r){
            x2[0][r] = xB[xo2 + r*XROW];
            x2[1][r] = xB[16*XROW + xo2 + r*XROW];
        }
    }

// one stream of layer0: reads h0f[ST][RB], writes h0f[ST][WB]
#define L0S(ST, RB, WB) { \
    bf16x8_t A0 = *(const bf16x8_t*)(&h0f[ST][RB][n][q*8]); \
    f32x4_t a0 = MFMA(A0, fbA, bv0 + x2[ST]*wx20); \
    f32x4_t a1 = MFMA(A0, fbB, bv1 + x2[ST]*wx21); \
    f32x4_t g0 = rcp4(exp4(a0*(-LOG2E)) + 1.f); \
    f32x4_t g1 = rcp4(exp4(a1*mco1) + 1.f)*aco1 + bco1; \
    f32x4_t p  = g0*g1; \
    p[0]=__shfl_xor(p[0],8,64); p[1]=__shfl_xor(p[1],8,64); \
    p[2]=__shfl_xor(p[2],8,64); p[3]=__shfl_xor(p[3],8,64); \
    cst[ST] = g0*cst[ST] + p; \
    float cA=cst[ST][0], oA=g1[0], cB=cst[ST][1], oB=g1[1]; \
    float c2=__shfl_xor(cst[ST][2],8,64), c3=__shfl_xor(cst[ST][3],8,64); \
    float o2=__shfl_xor(g1[2],8,64),  o3=__shfl_xor(g1[3],8,64); \
    if (!hi) { cA=c2; oA=o2; cB=c3; oB=o3; } \
    float hA = oA*ftanh_f(cA); \
    float hB = oB*ftanh_f(cB); \
    const int row = q*4 + (hi ? 0 : 2); \
    if (colok) { \
        h0f[ST][WB][row][u]   = (__bf16)hA; \
        h0f[ST][WB][row+1][u] = (__bf16)hB; \
    } \
}

// one stream of layer1: reads h0f/h1f[ST][RB], writes h1f[ST][WB]
#define L1S(ST, SS, RB, WB) { \
    bf16x8_t A1 = *(const bf16x8_t*)(&h0f[ST][RB][n][q*8]); \
    bf16x8_t A2 = *(const bf16x8_t*)(&h1f[ST][RB][n][q*8]); \
    f32x4_t d0 = MFMA(A2, fbC, bv0); d0 = MFMA(A1, fbA, d0); \
    f32x4_t d1 = MFMA(A2, fbD, bv1); d1 = MFMA(A1, fbB, d1); \
    f32x4_t g0 = rcp4(exp4(d0*(-LOG2E)) + 1.f); \
    f32x4_t g1 = rcp4(exp4(d1*mco1) + 1.f)*aco1 + bco1; \
    f32x4_t p  = g0*g1; \
    p[0]=__shfl_xor(p[0],8,64); p[1]=__shfl_xor(p[1],8,64); \
    p[2]=__shfl_xor(p[2],8,64); p[3]=__shfl_xor(p[3],8,64); \
    cst[ST] = g0*cst[ST] + p; \
    float cA=cst[ST][0], oA=g1[0], cB=cst[ST][1], oB=g1[1]; \
    float c2=__shfl_xor(cst[ST][2],8,64), c3=__shfl_xor(cst[ST][3],8,64); \
    float o2=__shfl_xor(g1[2],8,64),  o3=__shfl_xor(g1[3],8,64); \
    if (!hi) { cA=c2; oA=o2; cB=c3; oB=o3; } \
    float hA = oA*ftanh_f(cA); \
    float hB = oB*ftanh_f(cB); \
    const int row = q*4 + (hi ? 0 : 2); \
    if (colok) { \
        h1f[ST][WB][row][u]   = (__bf16)hA; \
        h1f[ST][WB][row+1][u] = (__bf16)hB; \
        if ((SS) == TT-1) { \
            h1_last[((ST)*16+row)*32+u]   = hA; \
            h1_last[((ST)*16+row+1)*32+u] = hB; \
        } \
    } \
}

#define STEP(SS, RB, WB, FIRST) do {                                           \
    if (grpA) {                                                                \
        /* prefetch x(s+2), both streams, before the heavy math */             \
        const int tpre = ((SS)+2 < TT) ? (SS)+2 : TT-1;                        \
        const float* xs = xB + 3*tpre;                                         \
        f32x4_t xnX, xnY;                                                      \
        _Pragma("unroll")                                                      \
        for (int r=0;r<4;++r){                                                 \
            xnX[r] = xs[xo2 + r*XROW];                                         \
            xnY[r] = xs[16*XROW + xo2 + r*XROW];                               \
        }                                                                      \
        float x01v = 0.f;                                                      \
        if (tid < 64) x01v = xs[xo01];                                         \
        L0S(0, RB, WB)                                                         \
        L0S(1, RB, WB)                                                         \
        if (tid < 64) {                                                        \
            int m = tid >> 1;                                                  \
            h0f[m>>4][WB][m&15][30+(tid&1)] = (__bf16)x01v;                    \
        }                                                                      \
        x2[0] = xnX;  x2[1] = xnY;                                             \
    } else if (!(FIRST)) {                                                     \
        L1S(0, SS, RB, WB)                                                     \
        L1S(1, SS, RB, WB)                                                     \
    }                                                                          \
    __syncthreads();                                                           \
} while (0)

    STEP(-1, 1, 0, 1);          // prologue: layer0 t=0 only
    #pragma unroll 1
    for (int s = 0; s < TT; s += 2) {
        STEP(s,   0, 1, 0);
        STEP(s+1, 1, 0, 0);
    }
#undef STEP
#undef L0S
#undef L1S

    // ---- FC head (32 rows, 512 threads) ----
    #pragma unroll
    for (int rep = 0; rep < 4; ++rep) {
        int idx = tid + rep*512;          // 32*64 outputs
        int m = idx >> 6, uu = idx & 63;
        float a = bfc1[uu];
        for (int k = 0; k < HID; ++k) a += h1_last[m*32+k] * Wfc1[uu*HID+k];
        zbuf[m*64+uu] = fmaxf(a, 0.f);
    }
    __syncthreads();
    #pragma unroll
    for (int rep = 0; rep < 2; ++rep) {
        int idx = tid + rep*512;          // 32*32 outputs
        int m = idx >> 5, v = idx & 31;
        float a = bfc2[v];
        for (int k = 0; k < 64; ++k) a += zbuf[m*64+k] * Wfc2[v*64+k];
        z2buf[m*32+v] = fmaxf(a, 0.f);
    }
    __syncthreads();
    if (tid < 32) {
        float a = bfc3[0];
        for (int k = 0; k < 32; ++k) a += z2buf[tid*32+k] * Wfc3[k];
        out[bbase + tid] = fsigmoid(a);
    }
}

extern "C" void kernel_launch(void* const* d_in, const int* in_sizes, int n_in,
                              void* d_out, int out_size, void* d_ws, size_t ws_size,
                              hipStream_t stream) {
    const float* x    = (const float*)d_in[0];
    const float* Wih0 = (const float*)d_in[1];
    const float* Whh0 = (const float*)d_in[2];
    const float* bih0 = (const float*)d_in[3];
    const float* bhh0 = (const float*)d_in[4];
    const float* Wih1 = (const float*)d_in[5];
    const float* Whh1 = (const float*)d_in[6];
    const float* bih1 = (const float*)d_in[7];
    const float* bhh1 = (const float*)d_in[8];
    const float* Wfc1 = (const float*)d_in[9];
    const float* bfc1 = (const float*)d_in[10];
    const float* Wfc2 = (const float*)d_in[11];
    const float* bfc2 = (const float*)d_in[12];
    const float* Wfc3 = (const float*)d_in[13];
    const float* bfc3 = (const float*)d_in[14];
    float* outp = (float*)d_out;

    hipLaunchKernelGGL(lstm_fused, dim3(256), dim3(512), 0, stream,
        x, Wih0, Whh0, bih0, bhh0, Wih1, Whh1, bih1, bhh1,
        Wfc1, bfc1, Wfc2, bfc2, Wfc3, bfc3, outp);
}

// Round 7
// 353.817 us; speedup vs baseline: 1.0082x; 1.0082x over previous
//
#include <hip/hip_runtime.h>

#define TT   256
#define HID  30
#define LOG2E 1.4426950408889634f
#define HS   56        // h-row stride in bf16
#define XROW (TT*3)

typedef __bf16 bf16x8_t __attribute__((ext_vector_type(8)));
typedef float  f32x4_t  __attribute__((ext_vector_type(4)));

__device__ __forceinline__ float fexp2(float x){
#if __has_builtin(__builtin_amdgcn_exp2f)
    return __builtin_amdgcn_exp2f(x);
#else
    return exp2f(x);
#endif
}
__device__ __forceinline__ float frcp(float x){
#if __has_builtin(__builtin_amdgcn_rcpf)
    return __builtin_amdgcn_rcpf(x);
#else
    return 1.f/x;
#endif
}
__device__ __forceinline__ float fsigmoid(float x){ return frcp(1.f + fexp2(-LOG2E*x)); }
__device__ __forceinline__ f32x4_t exp4(f32x4_t v){
    f32x4_t e; e[0]=fexp2(v[0]); e[1]=fexp2(v[1]); e[2]=fexp2(v[2]); e[3]=fexp2(v[3]); return e;
}
__device__ __forceinline__ f32x4_t rcp4(f32x4_t v){
    f32x4_t r; r[0]=frcp(v[0]); r[1]=frcp(v[1]); r[2]=frcp(v[2]); r[3]=frcp(v[3]); return r;
}
__device__ __forceinline__ f32x4_t sig4(f32x4_t v){ return rcp4(exp4(v*(-LOG2E)) + 1.f); }
__device__ __forceinline__ f32x4_t tanh4(f32x4_t v){ return rcp4(exp4(v*(-2.f*LOG2E)) + 1.f)*2.f - 1.f; }

#define MFMA(A,B,C) __builtin_amdgcn_mfma_f32_16x16x32_bf16(A,B,C,0,0,0)

// Producer/consumer 2-wave block, 16 batch rows, zero cross-wave gate traffic.
// Wave 0 computes ALL 120 layer-0 gates (t=s+1); wave 1 all layer-1 gates (t=s).
// Gate-major column tiling: tile t -> gate G=t>>1, units u=(t&1)*16+n. All 4
// gates of unit u for row m land in ONE lane -> c-update lane-local, no shfl,
// per-tile activation type compile-time. Only h crosses waves (LDS, dbuf),
// one 2-wave barrier per step. 512 blocks x 128 thr = 1024 waves = 1/SIMD.
__global__ __launch_bounds__(128)
void lstm_fused(const float* __restrict__ x,
    const float* __restrict__ Wih0, const float* __restrict__ Whh0,
    const float* __restrict__ bih0, const float* __restrict__ bhh0,
    const float* __restrict__ Wih1, const float* __restrict__ Whh1,
    const float* __restrict__ bih1, const float* __restrict__ bhh1,
    const float* __restrict__ Wfc1, const float* __restrict__ bfc1,
    const float* __restrict__ Wfc2, const float* __restrict__ bfc2,
    const float* __restrict__ Wfc3, const float* __restrict__ bfc3,
    float* __restrict__ out)
{
    __shared__ __align__(16) __bf16 h0f[2][16][HS];  // [buf][m][k]; k30,31 = x0,x1
    __shared__ __align__(16) __bf16 h1f[16][HS];     // single buffer (wave-1 private)
    __shared__ float h1_last[16*32];
    __shared__ float zbuf[16*64];
    __shared__ float z2buf[16*32];

    const int tid  = threadIdx.x;
    const int lane = tid & 63;
    const int wv   = tid >> 6;       // 0 = layer-0 wave, 1 = layer-1 wave
    const int n    = lane & 15;      // tile column
    const int q    = lane >> 4;      // quad: C/D rows q*4+r, A/B k-group q*8+j
    const int bbase = blockIdx.x * 16;

    // ---- resident B-fragments, gate-major tiling ----
    // tile t: gate G=t>>1 (i,f,g,o), unit u=(t&1)*16+n (valid u<30)
    bf16x8_t fb0[8];   // wave0: Whh0 (k30/31 = Wih0 cols 0,1) | wave1: Wih1
    bf16x8_t fb1[8];   // wave1: Whh1 (unused for wave0)
    float bias[8], wx2v[8];
    #pragma unroll
    for (int t = 0; t < 8; ++t) {
        const int G = t >> 1;
        const int u = (t & 1)*16 + n;
        const bool ok = (u < HID);
        const int row = G*HID + (ok ? u : 0);
        #pragma unroll
        for (int j = 0; j < 8; ++j) {
            const int k = q*8 + j;
            float v0 = 0.f, v1 = 0.f;
            if (ok) {
                if (wv == 0) {
                    v0 = (k < HID) ? Whh0[row*HID + k] : Wih0[row*3 + (k - HID)];
                } else if (k < HID) {
                    v0 = Wih1[row*HID + k];
                    v1 = Whh1[row*HID + k];
                }
            }
            fb0[t][j] = (__bf16)v0;
            fb1[t][j] = (__bf16)v1;
        }
        bias[t] = ok ? (wv == 0 ? bih0[row] + bhh0[row] : bih1[row] + bhh1[row]) : 0.f;
        wx2v[t] = (ok && wv == 0) ? Wih0[row*3 + 2] : 0.f;
    }

    f32x4_t cA = {0.f,0.f,0.f,0.f};   // c for units u=n,    rows q*4+r
    f32x4_t cB = {0.f,0.f,0.f,0.f};   // c for units u=16+n, rows q*4+r

    for (int i = tid; i < 2*16*HS; i += 128) (&h0f[0][0][0])[i] = (__bf16)0.f;
    for (int i = tid; i < 16*HS;   i += 128) (&h1f[0][0])[i]    = (__bf16)0.f;
    __syncthreads();
    if (tid < 32)   // x0,x1(t=0) into prologue read-buffer h0f[1]
        h0f[1][tid>>1][30+(tid&1)] = (__bf16)x[(size_t)(bbase + (tid>>1))*XROW + (tid&1)];
    __syncthreads();

    // x addressing: SGPR base + fixed per-lane offsets (wave 0 only)
    const float* xB  = x + (size_t)bbase*XROW;
    const int xo2  = (q*4)*XROW + 2;              // + r*XROW
    const int xo01 = (lane>>1)*XROW + (lane&1);   // lanes 0..31 -> 16 rows x {x0,x1}
    f32x4_t x2 = {0.f,0.f,0.f,0.f};               // x2(s+1)
    if (wv == 0) {
        #pragma unroll
        for (int r = 0; r < 4; ++r) x2[r] = xB[xo2 + r*XROW];
    }

#define ACTS_AND_STATE(d)                                                    \
    f32x4_t i0 = sig4(d[0]),  i1 = sig4(d[1]);                               \
    f32x4_t f0 = sig4(d[2]),  f1 = sig4(d[3]);                               \
    f32x4_t g0 = tanh4(d[4]), g1 = tanh4(d[5]);                              \
    f32x4_t o0 = sig4(d[6]),  o1 = sig4(d[7]);                               \
    cA = f0*cA + i0*g0;                                                      \
    cB = f1*cB + i1*g1;                                                      \
    f32x4_t hA = o0*tanh4(cA);                                               \
    f32x4_t hB = o1*tanh4(cB);

#define STEP(S, RB, WB) do {                                                 \
    if (wv == 0) {                                                           \
        if ((S) + 1 < TT) {   /* layer 0, t = S+1 */                         \
            bf16x8_t A0 = *(const bf16x8_t*)(&h0f[RB][n][q*8]);              \
            f32x4_t d[8];                                                    \
            _Pragma("unroll")                                                \
            for (int t = 0; t < 8; ++t) {                                    \
                f32x4_t cc = x2*wx2v[t] + bias[t];                           \
                d[t] = MFMA(A0, fb0[t], cc);                                 \
            }                                                                \
            const int tpre = ((S)+2 < TT) ? (S)+2 : TT-1;                    \
            const float* xs = xB + 3*tpre;                                   \
            f32x4_t x2n;                                                     \
            _Pragma("unroll")                                                \
            for (int r = 0; r < 4; ++r) x2n[r] = xs[xo2 + r*XROW];           \
            float x01v = (lane < 32) ? xs[xo01] : 0.f;                       \
            ACTS_AND_STATE(d)                                                \
            _Pragma("unroll")                                                \
            for (int r = 0; r < 4; ++r) h0f[WB][q*4+r][n] = (__bf16)hA[r];   \
            if (n < 14) {                                                    \
                _Pragma("unroll")                                            \
                for (int r = 0; r < 4; ++r) h0f[WB][q*4+r][16+n] = (__bf16)hB[r]; \
            }                                                                \
            if (lane < 32) h0f[WB][lane>>1][30+(lane&1)] = (__bf16)x01v;     \
            x2 = x2n;                                                        \
        }                                                                    \
    } else {                                                                 \
        if ((S) >= 0) {       /* layer 1, t = S */                           \
            bf16x8_t A1 = *(const bf16x8_t*)(&h0f[RB][n][q*8]);              \
            bf16x8_t A2 = *(const bf16x8_t*)(&h1f[n][q*8]);                  \
            f32x4_t d[8];                                                    \
            _Pragma("unroll")                                                \
            for (int t = 0; t < 8; ++t) {                                    \
                f32x4_t cc = {bias[t], bias[t], bias[t], bias[t]};           \
                cc   = MFMA(A1, fb0[t], cc);                                 \
                d[t] = MFMA(A2, fb1[t], cc);                                 \
            }                                                                \
            ACTS_AND_STATE(d)                                                \
            _Pragma("unroll")                                                \
            for (int r = 0; r < 4; ++r) h1f[q*4+r][n] = (__bf16)hA[r];       \
            if (n < 14) {                                                    \
                _Pragma("unroll")                                            \
                for (int r = 0; r < 4; ++r) h1f[q*4+r][16+n] = (__bf16)hB[r]; \
            }                                                                \
            if ((S) == TT-1) {                                               \
                _Pragma("unroll")                                            \
                for (int r = 0; r < 4; ++r) {                                \
                    h1_last[(q*4+r)*32 + n] = hA[r];                         \
                    if (n < 14) h1_last[(q*4+r)*32 + 16+n] = hB[r];          \
                }                                                            \
            }                                                                \
        }                                                                    \
    }                                                                        \
    __syncthreads();                                                         \
} while (0)

    STEP(-1, 1, 0);           // prologue: layer0 t=0 only
    #pragma unroll 1
    for (int s = 0; s < TT; s += 2) {
        STEP(s,   0, 1);
        STEP(s+1, 1, 0);
    }
#undef STEP
#undef ACTS_AND_STATE

    // ---- FC head (128 threads, 16 rows) ----
    #pragma unroll
    for (int rep = 0; rep < 8; ++rep) {
        int idx = tid + rep*128;          // 16*64 outputs
        int m = idx >> 6, uu = idx & 63;
        float a = bfc1[uu];
        for (int k = 0; k < HID; ++k) a += h1_last[m*32+k] * Wfc1[uu*HID+k];
        zbuf[m*64+uu] = fmaxf(a, 0.f);
    }
    __syncthreads();
    #pragma unroll
    for (int rep = 0; rep < 4; ++rep) {
        int idx = tid + rep*128;          // 16*32 outputs
        int m = idx >> 5, v = idx & 31;
        float a = bfc2[v];
        for (int k = 0; k < 64; ++k) a += zbuf[m*64+k] * Wfc2[v*64+k];
        z2buf[m*32+v] = fmaxf(a, 0.f);
    }
    __syncthreads();
    if (tid < 16) {
        float a = bfc3[0];
        for (int k = 0; k < 32; ++k) a += z2buf[tid*32+k] * Wfc3[k];
        out[bbase + tid] = fsigmoid(a);
    }
}

extern "C" void kernel_launch(void* const* d_in, const int* in_sizes, int n_in,
                              void* d_out, int out_size, void* d_ws, size_t ws_size,
                              hipStream_t stream) {
    const float* x    = (const float*)d_in[0];
    const float* Wih0 = (const float*)d_in[1];
    const float* Whh0 = (const float*)d_in[2];
    const float* bih0 = (const float*)d_in[3];
    const float* bhh0 = (const float*)d_in[4];
    const float* Wih1 = (const float*)d_in[5];
    const float* Whh1 = (const float*)d_in[6];
    const float* bih1 = (const float*)d_in[7];
    const float* bhh1 = (const float*)d_in[8];
    const float* Wfc1 = (const float*)d_in[9];
    const float* bfc1 = (const float*)d_in[10];
    const float* Wfc2 = (const float*)d_in[11];
    const float* bfc2 = (const float*)d_in[12];
    const float* Wfc3 = (const float*)d_in[13];
    const float* bfc3 = (const float*)d_in[14];
    float* outp = (float*)d_out;

    hipLaunchKernelGGL(lstm_fused, dim3(512), dim3(128), 0, stream,
        x, Wih0, Whh0, bih0, bhh0, Wih1, Whh1, bih1, bhh1,
        Wfc1, bfc1, Wfc2, bfc2, Wfc3, bfc3, outp);
}

// Round 8
// 337.015 us; speedup vs baseline: 1.0584x; 1.0499x over previous
//
#include <hip/hip_runtime.h>

#define TT   256
#define HID  30
#define LOG2E 1.4426950408889634f
#define HS   56        // h-row stride in bf16
#define XW   772       // x row stride in f32 inside LDS (768+4: bank-spread, 16B aligned)

typedef __bf16 bf16x8_t __attribute__((ext_vector_type(8)));
typedef float  f32x4_t  __attribute__((ext_vector_type(4)));

__device__ __forceinline__ float fexp2(float x){
#if __has_builtin(__builtin_amdgcn_exp2f)
    return __builtin_amdgcn_exp2f(x);
#else
    return exp2f(x);
#endif
}
__device__ __forceinline__ float frcp(float x){
#if __has_builtin(__builtin_amdgcn_rcpf)
    return __builtin_amdgcn_rcpf(x);
#else
    return 1.f/x;
#endif
}
__device__ __forceinline__ float fsigmoid(float x){ return frcp(1.f + fexp2(-LOG2E*x)); }
__device__ __forceinline__ f32x4_t exp4(f32x4_t v){
    f32x4_t e; e[0]=fexp2(v[0]); e[1]=fexp2(v[1]); e[2]=fexp2(v[2]); e[3]=fexp2(v[3]); return e;
}
__device__ __forceinline__ f32x4_t rcp4(f32x4_t v){
    f32x4_t r; r[0]=frcp(v[0]); r[1]=frcp(v[1]); r[2]=frcp(v[2]); r[3]=frcp(v[3]); return r;
}
__device__ __forceinline__ f32x4_t sig4(f32x4_t v){ return rcp4(exp4(v*(-LOG2E)) + 1.f); }
__device__ __forceinline__ f32x4_t tanh4(f32x4_t v){ return rcp4(exp4(v*(-2.f*LOG2E)) + 1.f)*2.f - 1.f; }

#define MFMA(A,B,C) __builtin_amdgcn_mfma_f32_16x16x32_bf16(A,B,C,0,0,0)

// R7 structure (2-wave producer/consumer, lane-local gates, zero shfl) +
// ALL x staged to LDS up front: the recurrence loop issues ZERO global-memory
// ops, so per-step __syncthreads() drains only lgkmcnt (fast ds), never the
// ~900-cycle cold-HBM vmcnt queue that was serializing R4-R7.
__global__ __launch_bounds__(128)
void lstm_fused(const float* __restrict__ x,
    const float* __restrict__ Wih0, const float* __restrict__ Whh0,
    const float* __restrict__ bih0, const float* __restrict__ bhh0,
    const float* __restrict__ Wih1, const float* __restrict__ Whh1,
    const float* __restrict__ bih1, const float* __restrict__ bhh1,
    const float* __restrict__ Wfc1, const float* __restrict__ bfc1,
    const float* __restrict__ Wfc2, const float* __restrict__ bfc2,
    const float* __restrict__ Wfc3, const float* __restrict__ bfc3,
    float* __restrict__ out)
{
    __shared__ __align__(16) __bf16 h0f[2][16][HS];  // [buf][m][k]; k30,31 = x0,x1
    __shared__ __align__(16) __bf16 h1f[16][HS];     // single buffer (wave-1 private)
    __shared__ __align__(16) float  sx[16*XW];       // x slice: [m][t*3+c], stride XW
    __shared__ float h1_last[16*32];
    __shared__ float zbuf[16*64];
    __shared__ float z2buf[16*32];

    const int tid  = threadIdx.x;
    const int lane = tid & 63;
    const int wv   = tid >> 6;       // 0 = layer-0 wave, 1 = layer-1 wave
    const int n    = lane & 15;      // tile column
    const int q    = lane >> 4;      // quad
    const int bbase = blockIdx.x * 16;

    // ---- stage x (16 rows x 768 f32 = 48 KB) into LDS, one time ----
    {
        const float* xB = x + (size_t)bbase * 768;
        #pragma unroll
        for (int it = 0; it < 24; ++it) {
            int flat = (it*128 + tid) * 4;           // 0..12284
            int m = flat / 768;
            int o = flat - m*768;
            const float4 v = *(const float4*)(xB + (size_t)m*768 + o);
            *(float4*)(&sx[m*XW + o]) = v;
        }
    }

    // ---- resident B-fragments, gate-major tiling ----
    // tile t: gate G=t>>1 (i,f,g,o), unit u=(t&1)*16+n (valid u<30)
    bf16x8_t fb0[8];   // wave0: Whh0 (k30/31 = Wih0 cols 0,1) | wave1: Wih1
    bf16x8_t fb1[8];   // wave1: Whh1
    float bias[8], wx2v[8];
    #pragma unroll
    for (int t = 0; t < 8; ++t) {
        const int G = t >> 1;
        const int u = (t & 1)*16 + n;
        const bool ok = (u < HID);
        const int row = G*HID + (ok ? u : 0);
        #pragma unroll
        for (int j = 0; j < 8; ++j) {
            const int k = q*8 + j;
            float v0 = 0.f, v1 = 0.f;
            if (ok) {
                if (wv == 0) {
                    v0 = (k < HID) ? Whh0[row*HID + k] : Wih0[row*3 + (k - HID)];
                } else if (k < HID) {
                    v0 = Wih1[row*HID + k];
                    v1 = Whh1[row*HID + k];
                }
            }
            fb0[t][j] = (__bf16)v0;
            fb1[t][j] = (__bf16)v1;
        }
        bias[t] = ok ? (wv == 0 ? bih0[row] + bhh0[row] : bih1[row] + bhh1[row]) : 0.f;
        wx2v[t] = (ok && wv == 0) ? Wih0[row*3 + 2] : 0.f;
    }

    f32x4_t cA = {0.f,0.f,0.f,0.f};   // c for units u=n,    rows q*4+r
    f32x4_t cB = {0.f,0.f,0.f,0.f};   // c for units u=16+n, rows q*4+r

    for (int i = tid; i < 2*16*HS; i += 128) (&h0f[0][0][0])[i] = (__bf16)0.f;
    for (int i = tid; i < 16*HS;   i += 128) (&h1f[0][0])[i]    = (__bf16)0.f;
    __syncthreads();       // staging + zero-init visible
    if (tid < 32)          // x0,x1(t=0) into prologue read-buffer h0f[1]
        h0f[1][tid>>1][30+(tid&1)] = (__bf16)sx[(tid>>1)*XW + (tid&1)];
    __syncthreads();

#define ACTS_AND_STATE(d)                                                    \
    f32x4_t i0 = sig4(d[0]),  i1 = sig4(d[1]);                               \
    f32x4_t f0 = sig4(d[2]),  f1 = sig4(d[3]);                               \
    f32x4_t g0 = tanh4(d[4]), g1 = tanh4(d[5]);                              \
    f32x4_t o0 = sig4(d[6]),  o1 = sig4(d[7]);                               \
    cA = f0*cA + i0*g0;                                                      \
    cB = f1*cB + i1*g1;                                                      \
    f32x4_t hA = o0*tanh4(cA);                                               \
    f32x4_t hB = o1*tanh4(cB);

#define STEP(S, RB, WB) do {                                                 \
    if (wv == 0) {                                                           \
        if ((S) + 1 < TT) {   /* layer 0, t = S+1 */                         \
            bf16x8_t A0 = *(const bf16x8_t*)(&h0f[RB][n][q*8]);              \
            f32x4_t x2;                                                      \
            _Pragma("unroll")                                                \
            for (int r = 0; r < 4; ++r)                                      \
                x2[r] = sx[(q*4+r)*XW + ((S)+1)*3 + 2];                      \
            f32x4_t d[8];                                                    \
            _Pragma("unroll")                                                \
            for (int t = 0; t < 8; ++t) {                                    \
                f32x4_t cc = x2*wx2v[t] + bias[t];                           \
                d[t] = MFMA(A0, fb0[t], cc);                                 \
            }                                                                \
            ACTS_AND_STATE(d)                                                \
            _Pragma("unroll")                                                \
            for (int r = 0; r < 4; ++r) h0f[WB][q*4+r][n] = (__bf16)hA[r];   \
            if (n < 14) {                                                    \
                _Pragma("unroll")                                            \
                for (int r = 0; r < 4; ++r) h0f[WB][q*4+r][16+n] = (__bf16)hB[r]; \
            }                                                                \
        }                                                                    \
    } else {                                                                 \
        /* stage x0,x1(S+2) into the write buffer (wave-1 side job) */       \
        {                                                                    \
            int tn = (S) + 2; if (tn > TT-1) tn = TT-1;                      \
            if (lane < 32) {                                                 \
                float xv = sx[(lane>>1)*XW + tn*3 + (lane&1)];               \
                h0f[WB][lane>>1][30+(lane&1)] = (__bf16)xv;                  \
            }                                                                \
        }                                                                    \
        if ((S) >= 0) {       /* layer 1, t = S */                           \
            bf16x8_t A1 = *(const bf16x8_t*)(&h0f[RB][n][q*8]);              \
            bf16x8_t A2 = *(const bf16x8_t*)(&h1f[n][q*8]);                  \
            f32x4_t d[8];                                                    \
            _Pragma("unroll")                                                \
            for (int t = 0; t < 8; ++t) {                                    \
                f32x4_t cc = {bias[t], bias[t], bias[t], bias[t]};           \
                cc   = MFMA(A1, fb0[t], cc);                                 \
                d[t] = MFMA(A2, fb1[t], cc);                                 \
            }                                                                \
            ACTS_AND_STATE(d)                                                \
            _Pragma("unroll")                                                \
            for (int r = 0; r < 4; ++r) h1f[q*4+r][n] = (__bf16)hA[r];       \
            if (n < 14) {                                                    \
                _Pragma("unroll")                                            \
                for (int r = 0; r < 4; ++r) h1f[q*4+r][16+n] = (__bf16)hB[r]; \
            }                                                                \
            if ((S) == TT-1) {                                               \
                _Pragma("unroll")                                            \
                for (int r = 0; r < 4; ++r) {                                \
                    h1_last[(q*4+r)*32 + n] = hA[r];                         \
                    if (n < 14) h1_last[(q*4+r)*32 + 16+n] = hB[r];          \
                }                                                            \
            }                                                                \
        }                                                                    \
    }                                                                        \
    __syncthreads();                                                         \
} while (0)

    STEP(-1, 1, 0);           // prologue: layer0 t=0 (+ stage x(1))
    #pragma unroll 1
    for (int s = 0; s < TT; s += 2) {
        STEP(s,   0, 1);
        STEP(s+1, 1, 0);
    }
#undef STEP
#undef ACTS_AND_STATE

    // ---- FC head (128 threads, 16 rows) ----
    #pragma unroll
    for (int rep = 0; rep < 8; ++rep) {
        int idx = tid + rep*128;          // 16*64 outputs
        int m = idx >> 6, uu = idx & 63;
        float a = bfc1[uu];
        for (int k = 0; k < HID; ++k) a += h1_last[m*32+k] * Wfc1[uu*HID+k];
        zbuf[m*64+uu] = fmaxf(a, 0.f);
    }
    __syncthreads();
    #pragma unroll
    for (int rep = 0; rep < 4; ++rep) {
        int idx = tid + rep*128;          // 16*32 outputs
        int m = idx >> 5, v = idx & 31;
        float a = bfc2[v];
        for (int k = 0; k < 64; ++k) a += zbuf[m*64+k] * Wfc2[v*64+k];
        z2buf[m*32+v] = fmaxf(a, 0.f);
    }
    __syncthreads();
    if (tid < 16) {
        float a = bfc3[0];
        for (int k = 0; k < 32; ++k) a += z2buf[tid*32+k] * Wfc3[k];
        out[bbase + tid] = fsigmoid(a);
    }
}

extern "C" void kernel_launch(void* const* d_in, const int* in_sizes, int n_in,
                              void* d_out, int out_size, void* d_ws, size_t ws_size,
                              hipStream_t stream) {
    const float* x    = (const float*)d_in[0];
    const float* Wih0 = (const float*)d_in[1];
    const float* Whh0 = (const float*)d_in[2];
    const float* bih0 = (const float*)d_in[3];
    const float* bhh0 = (const float*)d_in[4];
    const float* Wih1 = (const float*)d_in[5];
    const float* Whh1 = (const float*)d_in[6];
    const float* bih1 = (const float*)d_in[7];
    const float* bhh1 = (const float*)d_in[8];
    const float* Wfc1 = (const float*)d_in[9];
    const float* bfc1 = (const float*)d_in[10];
    const float* Wfc2 = (const float*)d_in[11];
    const float* bfc2 = (const float*)d_in[12];
    const float* Wfc3 = (const float*)d_in[13];
    const float* bfc3 = (const float*)d_in[14];
    float* outp = (float*)d_out;

    hipLaunchKernelGGL(lstm_fused, dim3(512), dim3(128), 0, stream,
        x, Wih0, Whh0, bih0, bhh0, Wih1, Whh1, bih1, bhh1,
        Wfc1, bfc1, Wfc2, bfc2, Wfc3, bfc3, outp);
}